// Round 12
// baseline (317.539 us; speedup 1.0000x reference)
//
#include <hip/hip_runtime.h>
#include <math.h>

// ---------------- problem constants ----------------
constexpr int Bn  = 128;
constexpr int Kd  = 65536;    // magnitude dim (phase half of feats is zeros)
constexpr int F1  = 128;
constexpr int F2  = 64;
constexpr int NM  = 3;
constexpr int Qd  = 256;
constexpr int NCH = 512;      // split-K chunks for big GEMM
constexpr int KC  = 128;      // k per chunk
constexpr int MSZ = 256 * 256;
constexpr int XSZ = 256 * 128;  // u32 slots per packed matrix

// Muon (growth) quintic Newton-Schulz coefficients
#define MA 3.4445f
#define MB (-4.7750f)
#define MC 2.0315f
// degree-9 convergent NS: x*(315 - 420y + 378y^2 - 180y^3 + 35y^4)/128, y=x^2
#define D9_0 (315.f / 128.f)
#define D9_1 (-420.f / 128.f)
#define D9_2 (378.f / 128.f)
#define D9_3 (-180.f / 128.f)
#define D9_4 (35.f / 128.f)

// ---------------- ws layout (float offsets) ----------------
constexpr size_t OFF_H1P = 0;                                    // 8,388,608
constexpr size_t OFF_H1  = OFF_H1P + (size_t)NCH * Bn * F1;
constexpr size_t OFF_SEL = OFF_H1 + (size_t)Bn * F1;
constexpr size_t OFF_PART= OFF_SEL + 128;                        // 192 -> 256
constexpr size_t OFF_PT  = OFF_PART + 256;                       // NM*MSZ f32 (P^T)
constexpr size_t OFF_XPA = OFF_PT + (size_t)NM * MSZ;            // NM*XSZ u32
constexpr size_t OFF_XTA = OFF_XPA + (size_t)NM * XSZ;
constexpr size_t OFF_XPB = OFF_XTA + (size_t)NM * XSZ;
constexpr size_t OFF_XTB = OFF_XPB + (size_t)NM * XSZ;

// ---------------- f16 helpers ----------------
typedef __fp16 half2_t __attribute__((ext_vector_type(2)));
union HU { half2_t h; unsigned int u; };
__device__ __forceinline__ unsigned int pkh(float x, float y) {
  HU v; v.h = __builtin_amdgcn_cvt_pkrtz(x, y); return v.u;
}
__device__ __forceinline__ half2_t uh(unsigned int u) { HU v; v.u = u; return v.h; }

#if __has_builtin(__builtin_amdgcn_fdot2)
#define FDOT2(a, b, c) __builtin_amdgcn_fdot2((a), (b), (c), false)
#else
#define FDOT2(a, b, c) ((c) + (float)(a)[0] * (float)(b)[0] + (float)(a)[1] * (float)(b)[1])
#endif

// ---------------- bf16 helpers (MFMA GEMM) ----------------
typedef short bf16x8 __attribute__((ext_vector_type(8)));
typedef float f32x4 __attribute__((ext_vector_type(4)));
__device__ __forceinline__ unsigned short bh(float x) {   // RNE fp32 -> bf16
  unsigned int bx = __float_as_uint(x);
  return (unsigned short)((bx + 0x7FFFu + ((bx >> 16) & 1u)) >> 16);
}
__device__ __forceinline__ float bf(unsigned short h) {
  return __uint_as_float((unsigned int)h << 16);
}

// ---------------- K1: split-K magnitude GEMM via bf16-split MFMA (R10, proven) ----------------
__global__ __launch_bounds__(256) void k_gemm1(const float* __restrict__ sp,
                                               const float* __restrict__ W1,
                                               float* __restrict__ h1p) {
  __shared__ short Ah[128][72];
  __shared__ short Al[128][72];
  __shared__ short Bh[128][72];
  __shared__ short Bl[128][72];
  const int t = threadIdx.x;
  const int w = t >> 6, l = t & 63;
  const int l15 = l & 15, lg = l >> 4;
  const int ch = blockIdx.x;
  const size_t k0 = (size_t)ch * KC;
  const int srow = t >> 4;
  const int skq  = (t & 15) * 4;

  f32x4 acc[2][8];
#pragma unroll
  for (int r = 0; r < 2; ++r)
#pragma unroll
    for (int c = 0; c < 8; ++c) acc[r][c] = (f32x4){0.f, 0.f, 0.f, 0.f};

#pragma unroll
  for (int sub = 0; sub < 2; ++sub) {
    __syncthreads();
    const size_t kb = k0 + sub * 64 + skq;
#pragma unroll
    for (int rep = 0; rep < 8; ++rep) {
      const int row = srow + rep * 16;
      const float4 av = *(const float4*)(sp + (size_t)row * Kd + kb);
      const float4 bv = *(const float4*)(W1 + (size_t)row * (2 * Kd) + kb);
      float va[4] = {fabsf(av.x), fabsf(av.y), fabsf(av.z), fabsf(av.w)};
      float vb[4] = {bv.x, bv.y, bv.z, bv.w};
      unsigned short ha[4], la[4], hb[4], lb[4];
#pragma unroll
      for (int e = 0; e < 4; ++e) {
        ha[e] = bh(va[e]); la[e] = bh(va[e] - bf(ha[e]));
        hb[e] = bh(vb[e]); lb[e] = bh(vb[e] - bf(hb[e]));
      }
      *(uint2*)&Ah[row][skq] = make_uint2((unsigned)ha[0] | ((unsigned)ha[1] << 16),
                                          (unsigned)ha[2] | ((unsigned)ha[3] << 16));
      *(uint2*)&Al[row][skq] = make_uint2((unsigned)la[0] | ((unsigned)la[1] << 16),
                                          (unsigned)la[2] | ((unsigned)la[3] << 16));
      *(uint2*)&Bh[row][skq] = make_uint2((unsigned)hb[0] | ((unsigned)hb[1] << 16),
                                          (unsigned)hb[2] | ((unsigned)hb[3] << 16));
      *(uint2*)&Bl[row][skq] = make_uint2((unsigned)lb[0] | ((unsigned)lb[1] << 16),
                                          (unsigned)lb[2] | ((unsigned)lb[3] << 16));
    }
    __syncthreads();
#pragma unroll
    for (int ks = 0; ks < 2; ++ks) {
      const int ko = ks * 32 + lg * 8;
      bf16x8 afh[2], afl[2];
#pragma unroll
      for (int r = 0; r < 2; ++r) {
        const int row = w * 32 + r * 16 + l15;
        afh[r] = *(const bf16x8*)&Ah[row][ko];
        afl[r] = *(const bf16x8*)&Al[row][ko];
      }
#pragma unroll
      for (int c = 0; c < 8; ++c) {
        const int col = c * 16 + l15;
        const bf16x8 bfh = *(const bf16x8*)&Bh[col][ko];
        const bf16x8 bfl = *(const bf16x8*)&Bl[col][ko];
#pragma unroll
        for (int r = 0; r < 2; ++r) {
          acc[r][c] = __builtin_amdgcn_mfma_f32_16x16x32_bf16(afh[r], bfh, acc[r][c], 0, 0, 0);
          acc[r][c] = __builtin_amdgcn_mfma_f32_16x16x32_bf16(afh[r], bfl, acc[r][c], 0, 0, 0);
          acc[r][c] = __builtin_amdgcn_mfma_f32_16x16x32_bf16(afl[r], bfh, acc[r][c], 0, 0, 0);
        }
      }
    }
  }

  float* outp = h1p + (size_t)ch * (Bn * F1);
#pragma unroll
  for (int r = 0; r < 2; ++r)
#pragma unroll
    for (int c = 0; c < 8; ++c) {
      const int col = c * 16 + l15;
#pragma unroll
      for (int reg = 0; reg < 4; ++reg) {
        const int row = w * 32 + r * 16 + lg * 4 + reg;
        outp[row * F1 + col] = acc[r][c][reg];
      }
    }
}

// ---------------- K1b: reduce partials + bias + relu (512 chunks) ----------------
__global__ __launch_bounds__(256) void k_red(const float* __restrict__ h1p,
                                             const float* __restrict__ b1,
                                             float* __restrict__ h1) {
  const int t = threadIdx.x;
  const int ol = t & 63;
  const int g = t >> 6;
  const int o = blockIdx.x * 64 + ol;
  double s = 0.0;
#pragma unroll 8
  for (int c = g * 128; c < g * 128 + 128; ++c)
    s += (double)h1p[(size_t)c * (Bn * F1) + o];
  __shared__ double red[4][64];
  red[g][ol] = s;
  __syncthreads();
  if (g == 0) {
    const double v = red[0][ol] + red[1][ol] + red[2][ol] + red[3][ol];
    const float r = (float)v + b1[o & 127];
    h1[o] = fmaxf(r, 0.f);
  }
}

// ---------------- K2: small MLP + syndrome + selection ----------------
__global__ __launch_bounds__(256) void k_mlp(const float* __restrict__ h1,
                                             const float* __restrict__ W2,
                                             const float* __restrict__ b2,
                                             const float* __restrict__ W3,
                                             const float* __restrict__ b3,
                                             int* __restrict__ sel) {
  const int t = threadIdx.x;
  const int b0 = blockIdx.x * 16;
  __shared__ float h2s[16 * 64];
  for (int o = t; o < 16 * 64; o += 256) {
    const int bl = o >> 6, j = o & 63;
    const float* hr = h1 + (b0 + bl) * F1;
    const float* wr = W2 + j * F1;
    float s = b2[j];
    for (int k = 0; k < F1; ++k) s += hr[k] * wr[k];
    h2s[o] = fmaxf(s, 0.f);
  }
  __syncthreads();
  if (t < 16) {
    const int b = b0 + t;
    float best = -1.f;
    int bi = 0;
    bool needed = false;
    for (int j = 0; j < 8; ++j) {
      double s = (double)b3[j];
      const float* wr = W3 + j * F2;
      for (int k = 0; k < F2; ++k) s += (double)h2s[t * F2 + k] * (double)wr[k];
      const float a = fabsf((float)s);
      if (a > 1e-4f) needed = true;
      if (a > best) { best = a; bi = j; }
    }
    sel[b] = needed ? (bi % NM) : -1;
  }
}

// ---------------- NS pack: ops -> XP (row-pairs) + XT (col-pairs) + ssq partials ----------------
// XP[r][pp] = f16pair(C[r][2pp], C[r][2pp+1]);  XT[p][rr] = f16pair(C[2rr][p], C[2rr+1][p])
__global__ __launch_bounds__(512) void k_pack(const float* __restrict__ ops,
                                              unsigned int* __restrict__ XPD,
                                              unsigned int* __restrict__ XTD,
                                              float* __restrict__ part) {
  const int m = blockIdx.x >> 6, g = blockIdx.x & 63;
  const float* C = ops + (size_t)m * MSZ;
  unsigned int* xp = XPD + (size_t)m * XSZ;
  unsigned int* xt = XTD + (size_t)m * XSZ;
  const int t = threadIdx.x;
  const int r0 = g * 4, p0 = g * 4;
  __shared__ float colb[4][260];
  __shared__ float rq[8];

  float ssq;
  {
    const int r = r0 + (t >> 7), pp = t & 127;
    const float2 v = *(const float2*)&C[r * 256 + pp * 2];
    ssq = v.x * v.x + v.y * v.y;
    xp[r * 128 + pp] = pkh(v.x, v.y);
  }
#pragma unroll
  for (int o = 32; o; o >>= 1) ssq += __shfl_down(ssq, o, 64);
  if ((t & 63) == 0) rq[t >> 6] = ssq;

  if (t < 256) {
    const float4 v = *(const float4*)&C[t * 256 + p0];
    colb[0][t] = v.x; colb[1][t] = v.y; colb[2][t] = v.z; colb[3][t] = v.w;
  }
  __syncthreads();
  {
    const int c = t >> 7, rr = t & 127;
    xt[(p0 + c) * 128 + rr] = pkh(colb[c][2 * rr], colb[c][2 * rr + 1]);
  }
  if (t == 0) {
    float s = 0.f;
#pragma unroll
    for (int q = 0; q < 8; ++q) s += rq[q];
    part[m * 64 + g] = s;
  }
}

// ---------------- pass core: o[c] = partial dot over this thread's k-half ----------------
// out[q][c] = sum_pairs dot2(M[q][kk], pk[c][kk]), kk in [h*64, h*64+64)
__device__ __forceinline__ void ns_pass(const unsigned int* __restrict__ M,
                                        const unsigned int (*__restrict__ pk)[132],
                                        const int q, const int h, float o[4]) {
  float a0 = 0, a1 = 0, a2 = 0, a3 = 0;
  const int kb = h * 64;
  const uint2* M2 = (const uint2*)(M + q * 128 + kb);
#pragma unroll 8
  for (int kk = 0; kk < 32; ++kk) {
    const uint2 mv = M2[kk];
    const half2_t m0 = uh(mv.x), m1 = uh(mv.y);
    const uint2 p0 = *(const uint2*)&pk[0][kb + 2 * kk];
    const uint2 p1 = *(const uint2*)&pk[1][kb + 2 * kk];
    const uint2 p2 = *(const uint2*)&pk[2][kb + 2 * kk];
    const uint2 p3 = *(const uint2*)&pk[3][kb + 2 * kk];
    a0 = FDOT2(m0, uh(p0.x), a0); a0 = FDOT2(m1, uh(p0.y), a0);
    a1 = FDOT2(m0, uh(p1.x), a1); a1 = FDOT2(m1, uh(p1.y), a1);
    a2 = FDOT2(m0, uh(p2.x), a2); a2 = FDOT2(m1, uh(p2.y), a2);
    a3 = FDOT2(m0, uh(p3.x), a3); a3 = FDOT2(m1, uh(p3.y), a3);
  }
  o[0] = a0; o[1] = a1; o[2] = a2; o[3] = a3;
}

// reduce 2-way + store f32 + repack into pk
#define REDUCE_PACK(DF)                                                     \
  if (h) { redp[0][q] = o[0]; redp[1][q] = o[1];                            \
           redp[2][q] = o[2]; redp[3][q] = o[3]; }                          \
  __syncthreads();                                                          \
  if (!h) {                                                                 \
    _Pragma("unroll")                                                       \
    for (int c = 0; c < 4; ++c) { o[c] += redp[c][q]; DF[c][q] = o[c]; }    \
  }                                                                         \
  __syncthreads();                                                          \
  { const int c_ = t >> 7, qq_ = t & 127;                                   \
    pk[c_][qq_] = pkh(DF[c_][2 * qq_], DF[c_][2 * qq_ + 1]); }              \
  __syncthreads();

// ---------------- NS Muon iteration (one dispatch, 4 passes, no Gram) ----------------
// block owns cols j0..j0+3: X' = ca*V0 + cb*X(X^T V0) + cc*X(X^T(X(X^T V0)))
__global__ __launch_bounds__(512) void k_it(const unsigned int* __restrict__ XP,
                                            const unsigned int* __restrict__ XT,
                                            unsigned int* __restrict__ XPn,
                                            unsigned int* __restrict__ XTn,
                                            const float* __restrict__ part,
                                            const int first) {
  const int m = blockIdx.x >> 6, g = blockIdx.x & 63, j0 = g * 4;
  const unsigned int* xp = XP + (size_t)m * XSZ;
  const unsigned int* xt = XT + (size_t)m * XSZ;
  unsigned int* xpn = XPn + (size_t)m * XSZ;
  unsigned int* xtn = XTn + (size_t)m * XSZ;
  const int t = threadIdx.x;
  const int q = t & 255, h = t >> 8;
  __shared__ float f0[4][260];          // V0 f32
  __shared__ float f1[4][260];          // U1 f32
  __shared__ float f2[4][260];          // scratch / result
  __shared__ unsigned int pk[4][132];   // packed pass operand
  __shared__ float redp[4][260];
  __shared__ float sS;

  float ca = MA, cb = MB, cc = MC;
  if (first) {
    if (t < 64) {
      float v = part[m * 64 + t];
#pragma unroll
      for (int o = 32; o; o >>= 1) v += __shfl_down(v, o, 64);
      if (t == 0) sS = v;
    }
    __syncthreads();
    const float s = 0.15f * sqrtf(sS);   // 1.2 * 2||C||_F / sqrt(256)
    const float is = 1.f / s, is2 = is * is;
    ca = MA * is; cb = MB * is * is2; cc = MC * is * is2 * is2;
  }

  {  // stage V0 (cols j0..j0+3): f32 + packed-along-r (directly = xt rows)
    const int c = t >> 7, rr = t & 127;
    const unsigned int wv = xt[(j0 + c) * 128 + rr];
    const half2_t hh = uh(wv);
    f0[c][2 * rr]     = (float)hh[0];
    f0[c][2 * rr + 1] = (float)hh[1];
    pk[c][rr] = wv;
  }
  __syncthreads();

  float o[4];
  ns_pass(xt, pk, q, h, o);  REDUCE_PACK(f2);   // W1 = X^T V0
  ns_pass(xp, pk, q, h, o);  REDUCE_PACK(f1);   // U1 = X W1
  ns_pass(xt, pk, q, h, o);  REDUCE_PACK(f2);   // W2 = X^T U1
  ns_pass(xp, pk, q, h, o);                     // U2 = X W2
  if (h) { redp[0][q] = o[0]; redp[1][q] = o[1]; redp[2][q] = o[2]; redp[3][q] = o[3]; }
  __syncthreads();
  if (!h) {
#pragma unroll
    for (int c = 0; c < 4; ++c) {
      const float u2 = o[c] + redp[c][q];
      f2[c][q] = ca * f0[c][q] + cb * f1[c][q] + cc * u2;
    }
  }
  __syncthreads();

  {  // write XT' rows j0..j0+3 (pack along r)
    const int c = t >> 7, rr = t & 127;
    xtn[(j0 + c) * 128 + rr] = pkh(f2[c][2 * rr], f2[c][2 * rr + 1]);
  }
  if (t < 256) {  // write XP' column-pairs (j0,j0+1), (j0+2,j0+3)
    xpn[t * 128 + (j0 >> 1)]     = pkh(f2[0][t], f2[1][t]);
    xpn[t * 128 + (j0 >> 1) + 1] = pkh(f2[2][t], f2[3][t]);
  }
}

// ---------------- NS degree-9 convergent final: out = sum c_p B^p V0, writes P^T fp32 ----------------
__global__ __launch_bounds__(512) void k_d9(const unsigned int* __restrict__ XP,
                                            const unsigned int* __restrict__ XT,
                                            float* __restrict__ PT) {
  const int m = blockIdx.x >> 6, g = blockIdx.x & 63, j0 = g * 4;
  const unsigned int* xp = XP + (size_t)m * XSZ;
  const unsigned int* xt = XT + (size_t)m * XSZ;
  float* ptm = PT + (size_t)m * MSZ;
  const int t = threadIdx.x;
  const int q = t & 255, h = t >> 8;
  __shared__ float f0[4][260];
  __shared__ float f2[4][260];
  __shared__ unsigned int pk[4][132];
  __shared__ float redp[4][260];

  {
    const int c = t >> 7, rr = t & 127;
    const unsigned int wv = xt[(j0 + c) * 128 + rr];
    const half2_t hh = uh(wv);
    f0[c][2 * rr]     = (float)hh[0];
    f0[c][2 * rr + 1] = (float)hh[1];
    pk[c][rr] = wv;
  }
  __syncthreads();

  float outv[4] = {0.f, 0.f, 0.f, 0.f};
  if (!h) {
#pragma unroll
    for (int c = 0; c < 4; ++c) outv[c] = D9_0 * f0[c][q];
  }

  float o[4];
  // u1 = B V0
  ns_pass(xt, pk, q, h, o);  REDUCE_PACK(f2);
  ns_pass(xp, pk, q, h, o);  REDUCE_PACK(f2);
  if (!h) { outv[0] += D9_1 * o[0]; outv[1] += D9_1 * o[1]; outv[2] += D9_1 * o[2]; outv[3] += D9_1 * o[3]; }
  // u2 = B^2 V0
  ns_pass(xt, pk, q, h, o);  REDUCE_PACK(f2);
  ns_pass(xp, pk, q, h, o);  REDUCE_PACK(f2);
  if (!h) { outv[0] += D9_2 * o[0]; outv[1] += D9_2 * o[1]; outv[2] += D9_2 * o[2]; outv[3] += D9_2 * o[3]; }
  // u3 = B^3 V0
  ns_pass(xt, pk, q, h, o);  REDUCE_PACK(f2);
  ns_pass(xp, pk, q, h, o);  REDUCE_PACK(f2);
  if (!h) { outv[0] += D9_3 * o[0]; outv[1] += D9_3 * o[1]; outv[2] += D9_3 * o[2]; outv[3] += D9_3 * o[3]; }
  // u4 = B^4 V0
  ns_pass(xt, pk, q, h, o);  REDUCE_PACK(f2);
  ns_pass(xp, pk, q, h, o);
  if (h) { redp[0][q] = o[0]; redp[1][q] = o[1]; redp[2][q] = o[2]; redp[3][q] = o[3]; }
  __syncthreads();
  if (!h) {
#pragma unroll
    for (int c = 0; c < 4; ++c) {
      outv[c] += D9_4 * (o[c] + redp[c][q]);
      ptm[(j0 + c) * 256 + q] = outv[c];   // PT[j][i] = P[i][j]
    }
  }
}

// ---------------- K4: output assembly (reads P^T, coalesced) ----------------
__global__ __launch_bounds__(256) void k_out(const float* __restrict__ sp,
                                             const float* __restrict__ PT,
                                             const int* __restrict__ sel,
                                             float* __restrict__ out) {
  const int t = threadIdx.x;
  if (blockIdx.x < 128) {
    const int b = blockIdx.x;
    __shared__ float hd[256];
    hd[t] = sp[(size_t)b * Kd + t];
    __syncthreads();
    const int s = sel[b];
    if (s < 0) {
      out[(size_t)b * Kd + t] = hd[t];
    } else {
      const float* pt = PT + (size_t)s * MSZ;
      float acc = 0.f;
#pragma unroll 8
      for (int j = 0; j < 256; ++j) acc += pt[j * 256 + t] * hd[j];
      out[(size_t)b * Kd + t] = hd[t] + 0.1f * acc;
    }
  } else {
    const int ci = blockIdx.x - 128;
    const float4* in4 = (const float4*)sp;
    float4* out4 = (float4*)out;
    const int total = Bn * (Kd / 4);
    for (int i = ci * 256 + t; i < total; i += 2048 * 256) {
      const int pos = i & ((Kd / 4) - 1);
      if (pos >= Qd / 4) out4[i] = in4[i];
    }
  }
}

// ---------------- host ----------------
extern "C" void kernel_launch(void* const* d_in, const int* in_sizes, int n_in,
                              void* d_out, int out_size, void* d_ws, size_t ws_size,
                              hipStream_t stream) {
  (void)in_sizes; (void)n_in; (void)out_size; (void)ws_size;
  const float* sp = (const float*)d_in[0];
  const float* W1 = (const float*)d_in[1];
  const float* b1 = (const float*)d_in[2];
  const float* W2 = (const float*)d_in[3];
  const float* b2 = (const float*)d_in[4];
  const float* W3 = (const float*)d_in[5];
  const float* b3 = (const float*)d_in[6];
  const float* ops = (const float*)d_in[7];
  float* out = (float*)d_out;
  float* ws = (float*)d_ws;

  float* h1p  = ws + OFF_H1P;
  float* h1   = ws + OFF_H1;
  int*   sel  = (int*)(ws + OFF_SEL);
  float* part = ws + OFF_PART;
  float* PT   = ws + OFF_PT;
  unsigned int* XPa = (unsigned int*)(ws + OFF_XPA);
  unsigned int* XTa = (unsigned int*)(ws + OFF_XTA);
  unsigned int* XPb = (unsigned int*)(ws + OFF_XPB);
  unsigned int* XTb = (unsigned int*)(ws + OFF_XTB);

  k_gemm1<<<NCH, 256, 0, stream>>>(sp, W1, h1p);
  k_red<<<256, 256, 0, stream>>>(h1p, b1, h1);
  k_mlp<<<8, 256, 0, stream>>>(h1, W2, b2, W3, b3, sel);

  k_pack<<<192, 512, 0, stream>>>(ops, XPa, XTa, part);
  // 7 Muon iterations (first folds the 1/s scale), then degree-9 convergent
  k_it<<<192, 512, 0, stream>>>(XPa, XTa, XPb, XTb, part, 1);
  unsigned int *XPc = XPb, *XTc = XTb, *XPn = XPa, *XTn = XTa;
  for (int it = 1; it < 7; ++it) {
    k_it<<<192, 512, 0, stream>>>(XPc, XTc, XPn, XTn, part, 0);
    unsigned int* tp = XPc; XPc = XPn; XPn = tp;
    unsigned int* tt = XTc; XTc = XTn; XTn = tt;
  }
  k_d9<<<192, 512, 0, stream>>>(XPc, XTc, PT);

  k_out<<<128 + 2048, 256, 0, stream>>>(sp, PT, sel, out);
}

// Round 13
// 266.513 us; speedup vs baseline: 1.1915x; 1.1915x over previous
//
#include <hip/hip_runtime.h>
#include <math.h>

// ---------------- problem constants ----------------
constexpr int Bn  = 128;
constexpr int Kd  = 65536;    // magnitude dim (phase half of feats is zeros)
constexpr int F1  = 128;
constexpr int F2  = 64;
constexpr int NM  = 3;
constexpr int Qd  = 256;
constexpr int NCH = 512;      // split-K chunks for big GEMM
constexpr int KC  = 128;      // k per chunk
constexpr int MSZ = 256 * 256;
constexpr int XSZ = 256 * 128;  // u32 slots per packed matrix

// Muon (growth) quintic Newton-Schulz coefficients
#define MA 3.4445f
#define MB (-4.7750f)
#define MC 2.0315f
// degree-9 convergent NS: x*(315 - 420y + 378y^2 - 180y^3 + 35y^4)/128, y=x^2
#define D9_0 (315.f / 128.f)
#define D9_1 (-420.f / 128.f)
#define D9_2 (378.f / 128.f)
#define D9_3 (-180.f / 128.f)
#define D9_4 (35.f / 128.f)

// ---------------- ws layout (float offsets) ----------------
constexpr size_t OFF_H1P = 0;                                    // 8,388,608
constexpr size_t OFF_H1  = OFF_H1P + (size_t)NCH * Bn * F1;
constexpr size_t OFF_SEL = OFF_H1 + (size_t)Bn * F1;
constexpr size_t OFF_PART= OFF_SEL + 128;                        // 192 -> 256
constexpr size_t OFF_PT  = OFF_PART + 256;                       // NM*MSZ f32 (P^T)
constexpr size_t OFF_XPA = OFF_PT + (size_t)NM * MSZ;            // NM*XSZ u32
constexpr size_t OFF_XPB = OFF_XPA + (size_t)NM * XSZ;

// ---------------- f16 helpers ----------------
typedef __fp16 half2_t __attribute__((ext_vector_type(2)));
union HU { half2_t h; unsigned int u; };
__device__ __forceinline__ unsigned int pkh(float x, float y) {
  HU v; v.h = __builtin_amdgcn_cvt_pkrtz(x, y); return v.u;
}
__device__ __forceinline__ half2_t uh(unsigned int u) { HU v; v.u = u; return v.h; }

#if __has_builtin(__builtin_amdgcn_fdot2)
#define FDOT2(a, b, c) __builtin_amdgcn_fdot2((a), (b), (c), false)
#else
#define FDOT2(a, b, c) ((c) + (float)(a)[0] * (float)(b)[0] + (float)(a)[1] * (float)(b)[1])
#endif

// ---------------- bf16 helpers (MFMA GEMM) ----------------
typedef short bf16x8 __attribute__((ext_vector_type(8)));
typedef float f32x4 __attribute__((ext_vector_type(4)));
__device__ __forceinline__ unsigned short bh(float x) {   // RNE fp32 -> bf16
  unsigned int bx = __float_as_uint(x);
  return (unsigned short)((bx + 0x7FFFu + ((bx >> 16) & 1u)) >> 16);
}
__device__ __forceinline__ float bf(unsigned short h) {
  return __uint_as_float((unsigned int)h << 16);
}

// ---------------- K1: split-K magnitude GEMM via bf16-split MFMA (R10, proven) ----------------
__global__ __launch_bounds__(256) void k_gemm1(const float* __restrict__ sp,
                                               const float* __restrict__ W1,
                                               float* __restrict__ h1p) {
  __shared__ short Ah[128][72];
  __shared__ short Al[128][72];
  __shared__ short Bh[128][72];
  __shared__ short Bl[128][72];
  const int t = threadIdx.x;
  const int w = t >> 6, l = t & 63;
  const int l15 = l & 15, lg = l >> 4;
  const int ch = blockIdx.x;
  const size_t k0 = (size_t)ch * KC;
  const int srow = t >> 4;
  const int skq  = (t & 15) * 4;

  f32x4 acc[2][8];
#pragma unroll
  for (int r = 0; r < 2; ++r)
#pragma unroll
    for (int c = 0; c < 8; ++c) acc[r][c] = (f32x4){0.f, 0.f, 0.f, 0.f};

#pragma unroll
  for (int sub = 0; sub < 2; ++sub) {
    __syncthreads();
    const size_t kb = k0 + sub * 64 + skq;
#pragma unroll
    for (int rep = 0; rep < 8; ++rep) {
      const int row = srow + rep * 16;
      const float4 av = *(const float4*)(sp + (size_t)row * Kd + kb);
      const float4 bv = *(const float4*)(W1 + (size_t)row * (2 * Kd) + kb);
      float va[4] = {fabsf(av.x), fabsf(av.y), fabsf(av.z), fabsf(av.w)};
      float vb[4] = {bv.x, bv.y, bv.z, bv.w};
      unsigned short ha[4], la[4], hb[4], lb[4];
#pragma unroll
      for (int e = 0; e < 4; ++e) {
        ha[e] = bh(va[e]); la[e] = bh(va[e] - bf(ha[e]));
        hb[e] = bh(vb[e]); lb[e] = bh(vb[e] - bf(hb[e]));
      }
      *(uint2*)&Ah[row][skq] = make_uint2((unsigned)ha[0] | ((unsigned)ha[1] << 16),
                                          (unsigned)ha[2] | ((unsigned)ha[3] << 16));
      *(uint2*)&Al[row][skq] = make_uint2((unsigned)la[0] | ((unsigned)la[1] << 16),
                                          (unsigned)la[2] | ((unsigned)la[3] << 16));
      *(uint2*)&Bh[row][skq] = make_uint2((unsigned)hb[0] | ((unsigned)hb[1] << 16),
                                          (unsigned)hb[2] | ((unsigned)hb[3] << 16));
      *(uint2*)&Bl[row][skq] = make_uint2((unsigned)lb[0] | ((unsigned)lb[1] << 16),
                                          (unsigned)lb[2] | ((unsigned)lb[3] << 16));
    }
    __syncthreads();
#pragma unroll
    for (int ks = 0; ks < 2; ++ks) {
      const int ko = ks * 32 + lg * 8;
      bf16x8 afh[2], afl[2];
#pragma unroll
      for (int r = 0; r < 2; ++r) {
        const int row = w * 32 + r * 16 + l15;
        afh[r] = *(const bf16x8*)&Ah[row][ko];
        afl[r] = *(const bf16x8*)&Al[row][ko];
      }
#pragma unroll
      for (int c = 0; c < 8; ++c) {
        const int col = c * 16 + l15;
        const bf16x8 bfh = *(const bf16x8*)&Bh[col][ko];
        const bf16x8 bfl = *(const bf16x8*)&Bl[col][ko];
#pragma unroll
        for (int r = 0; r < 2; ++r) {
          acc[r][c] = __builtin_amdgcn_mfma_f32_16x16x32_bf16(afh[r], bfh, acc[r][c], 0, 0, 0);
          acc[r][c] = __builtin_amdgcn_mfma_f32_16x16x32_bf16(afh[r], bfl, acc[r][c], 0, 0, 0);
          acc[r][c] = __builtin_amdgcn_mfma_f32_16x16x32_bf16(afl[r], bfh, acc[r][c], 0, 0, 0);
        }
      }
    }
  }

  float* outp = h1p + (size_t)ch * (Bn * F1);
#pragma unroll
  for (int r = 0; r < 2; ++r)
#pragma unroll
    for (int c = 0; c < 8; ++c) {
      const int col = c * 16 + l15;
#pragma unroll
      for (int reg = 0; reg < 4; ++reg) {
        const int row = w * 32 + r * 16 + lg * 4 + reg;
        outp[row * F1 + col] = acc[r][c][reg];
      }
    }
}

// ---------------- K1b: reduce partials + bias + relu (512 chunks) ----------------
__global__ __launch_bounds__(256) void k_red(const float* __restrict__ h1p,
                                             const float* __restrict__ b1,
                                             float* __restrict__ h1) {
  const int t = threadIdx.x;
  const int ol = t & 63;
  const int g = t >> 6;
  const int o = blockIdx.x * 64 + ol;
  double s = 0.0;
#pragma unroll 8
  for (int c = g * 128; c < g * 128 + 128; ++c)
    s += (double)h1p[(size_t)c * (Bn * F1) + o];
  __shared__ double red[4][64];
  red[g][ol] = s;
  __syncthreads();
  if (g == 0) {
    const double v = red[0][ol] + red[1][ol] + red[2][ol] + red[3][ol];
    const float r = (float)v + b1[o & 127];
    h1[o] = fmaxf(r, 0.f);
  }
}

// ---------------- K2: small MLP + syndrome + selection ----------------
__global__ __launch_bounds__(256) void k_mlp(const float* __restrict__ h1,
                                             const float* __restrict__ W2,
                                             const float* __restrict__ b2,
                                             const float* __restrict__ W3,
                                             const float* __restrict__ b3,
                                             int* __restrict__ sel) {
  const int t = threadIdx.x;
  const int b0 = blockIdx.x * 16;
  __shared__ float h2s[16 * 64];
  for (int o = t; o < 16 * 64; o += 256) {
    const int bl = o >> 6, j = o & 63;
    const float* hr = h1 + (b0 + bl) * F1;
    const float* wr = W2 + j * F1;
    float s = b2[j];
    for (int k = 0; k < F1; ++k) s += hr[k] * wr[k];
    h2s[o] = fmaxf(s, 0.f);
  }
  __syncthreads();
  if (t < 16) {
    const int b = b0 + t;
    float best = -1.f;
    int bi = 0;
    bool needed = false;
    for (int j = 0; j < 8; ++j) {
      double s = (double)b3[j];
      const float* wr = W3 + j * F2;
      for (int k = 0; k < F2; ++k) s += (double)h2s[t * F2 + k] * (double)wr[k];
      const float a = fabsf((float)s);
      if (a > 1e-4f) needed = true;
      if (a > best) { best = a; bi = j; }
    }
    sel[b] = needed ? (bi % NM) : -1;
  }
}

// ---------------- NS pack: ops -> XP (row f16-pairs) + ssq partials ----------------
__global__ __launch_bounds__(512) void k_pack(const float* __restrict__ ops,
                                              unsigned int* __restrict__ XPD,
                                              float* __restrict__ part) {
  const int m = blockIdx.x >> 6, g = blockIdx.x & 63;
  const float* C = ops + (size_t)m * MSZ;
  unsigned int* xp = XPD + (size_t)m * XSZ;
  const int t = threadIdx.x;
  __shared__ float rq[8];

  const int r = g * 4 + (t >> 7), pp = t & 127;
  const float2 v = *(const float2*)&C[r * 256 + pp * 2];
  float ssq = v.x * v.x + v.y * v.y;
  xp[r * 128 + pp] = pkh(v.x, v.y);
#pragma unroll
  for (int o = 32; o; o >>= 1) ssq += __shfl_down(ssq, o, 64);
  if ((t & 63) == 0) rq[t >> 6] = ssq;
  __syncthreads();
  if (t == 0) {
    float s = 0.f;
#pragma unroll
    for (int q = 0; q < 8; ++q) s += rq[q];
    part[m * 64 + g] = s;
  }
}

// ---------------- LDS pass helpers ----------------
// col-pass: W = X^T V for 4 RHS; thread = (col-pair pp = t>>2, quarter qtr = t&3)
__device__ __forceinline__ void col_pass(const unsigned int (*__restrict__ XL)[131],
                                         const float (*__restrict__ V)[4],
                                         uint4* __restrict__ pkT,
                                         const int t) {
  const int pp = t >> 2, qtr = t & 3;
  float a00=0,a01=0,a10=0,a11=0,a20=0,a21=0,a30=0,a31=0;
  const int rb = qtr * 64;
#pragma unroll 8
  for (int i = 0; i < 64; ++i) {
    const int r = rb + i;
    const half2_t xh = uh(XL[r][pp]);
    const float x0 = (float)xh[0], x1 = (float)xh[1];
    const float4 vr = *(const float4*)&V[r][0];
    a00 += x0 * vr.x; a01 += x1 * vr.x;
    a10 += x0 * vr.y; a11 += x1 * vr.y;
    a20 += x0 * vr.z; a21 += x1 * vr.z;
    a30 += x0 * vr.w; a31 += x1 * vr.w;
  }
#define RED4(v) v += __shfl_down(v, 1, 4); v += __shfl_down(v, 2, 4);
  RED4(a00) RED4(a01) RED4(a10) RED4(a11)
  RED4(a20) RED4(a21) RED4(a30) RED4(a31)
#undef RED4
  if (qtr == 0)
    pkT[pp] = make_uint4(pkh(a00, a01), pkh(a10, a11), pkh(a20, a21), pkh(a30, a31));
}

// row-pass: U = X W for 4 RHS; thread = (row q = t>>1, half hh = t&1)
// after the shfl, even lanes (hh==0) hold the full dot for row q.
__device__ __forceinline__ void row_pass(const unsigned int (*__restrict__ XL)[131],
                                         const uint4* __restrict__ pkT,
                                         const int t, float b[4]) {
  const int q = t >> 1, hh = t & 1;
  float b0 = 0, b1 = 0, b2 = 0, b3 = 0;
  const int kb = hh * 64;
#pragma unroll 8
  for (int kk = 0; kk < 64; ++kk) {
    const half2_t xh = uh(XL[q][kb + kk]);
    const uint4 wv = pkT[kb + kk];
    b0 = FDOT2(xh, uh(wv.x), b0);
    b1 = FDOT2(xh, uh(wv.y), b1);
    b2 = FDOT2(xh, uh(wv.z), b2);
    b3 = FDOT2(xh, uh(wv.w), b3);
  }
  b0 += __shfl_down(b0, 1, 2);
  b1 += __shfl_down(b1, 1, 2);
  b2 += __shfl_down(b2, 1, 2);
  b3 += __shfl_down(b3, 1, 2);
  b[0] = b0; b[1] = b1; b[2] = b2; b[3] = b3;
}

// ---------------- NS Muon iteration: one dispatch, X LDS-resident ----------------
// block owns cols j0..j0+3: X' = ca*V0 + cb*X(X^T V0) + cc*X(X^T(X(X^T V0)))
__global__ __launch_bounds__(512) void k_it(const unsigned int* __restrict__ XP,
                                            unsigned int* __restrict__ XPn,
                                            const float* __restrict__ part,
                                            const int first) {
  const int m = blockIdx.x >> 6, g = blockIdx.x & 63;
  const unsigned int* xp = XP + (size_t)m * XSZ;
  unsigned int* xpn = XPn + (size_t)m * XSZ;
  const int t = threadIdx.x;

  __shared__ unsigned int XL[256][131];
  __shared__ float fV[256][4];
  __shared__ float fU[256][4];
  __shared__ uint4 pkT[132];
  __shared__ float sSh;

  if (first && t < 64) {
    float v = part[m * 64 + t];
#pragma unroll
    for (int o = 32; o; o >>= 1) v += __shfl_down(v, o, 64);
    if (t == 0) sSh = v;
  }

  // stage X into LDS (coalesced flat copy)
#pragma unroll 8
  for (int i = 0; i < 64; ++i) {
    const int flat = i * 512 + t;
    XL[flat >> 7][flat & 127] = xp[flat];
  }
  __syncthreads();

  float ca = MA, cb = MB, cc = MC;
  if (first) {
    const float s = 0.15f * sqrtf(sSh);  // 1.2 * 2||C||_F / sqrt(256)
    const float is = 1.f / s, is2 = is * is;
    ca = MA * is; cb = MB * is * is2; cc = MC * is * is2 * is2;
  }

  // stage V0 = X[:, 4g..4g+3] (f32)
  if (t < 256) {
    const half2_t h0 = uh(XL[t][2 * g]), h1 = uh(XL[t][2 * g + 1]);
    fV[t][0] = (float)h0[0]; fV[t][1] = (float)h0[1];
    fV[t][2] = (float)h1[0]; fV[t][3] = (float)h1[1];
  }
  __syncthreads();

  col_pass(XL, fV, pkT, t);   // W1 = X^T V0
  __syncthreads();
  float b[4];
  row_pass(XL, pkT, t, b);    // U1 = X W1
  const int q = t >> 1, hh = t & 1;
  if (!hh) *(float4*)&fU[q][0] = make_float4(b[0], b[1], b[2], b[3]);
  __syncthreads();

  col_pass(XL, fU, pkT, t);   // W2 = X^T U1
  __syncthreads();
  row_pass(XL, pkT, t, b);    // U2 = X W2
  if (!hh) {
    const float4 v0 = *(const float4*)&fV[q][0];
    const float4 u1 = *(const float4*)&fU[q][0];
    const float r0 = ca * v0.x + cb * u1.x + cc * b[0];
    const float r1 = ca * v0.y + cb * u1.y + cc * b[1];
    const float r2 = ca * v0.z + cb * u1.z + cc * b[2];
    const float r3 = ca * v0.w + cb * u1.w + cc * b[3];
    xpn[q * 128 + 2 * g]     = pkh(r0, r1);
    xpn[q * 128 + 2 * g + 1] = pkh(r2, r3);
  }
}

// ---------------- NS degree-9 convergent final: writes P^T fp32 ----------------
__global__ __launch_bounds__(512) void k_d9(const unsigned int* __restrict__ XP,
                                            float* __restrict__ PT) {
  const int m = blockIdx.x >> 6, g = blockIdx.x & 63;
  const unsigned int* xp = XP + (size_t)m * XSZ;
  float* ptm = PT + (size_t)m * MSZ;
  const int t = threadIdx.x;

  __shared__ unsigned int XL[256][131];
  __shared__ float fV[256][4];
  __shared__ uint4 pkT[132];

#pragma unroll 8
  for (int i = 0; i < 64; ++i) {
    const int flat = i * 512 + t;
    XL[flat >> 7][flat & 127] = xp[flat];
  }
  __syncthreads();
  if (t < 256) {
    const half2_t h0 = uh(XL[t][2 * g]), h1 = uh(XL[t][2 * g + 1]);
    fV[t][0] = (float)h0[0]; fV[t][1] = (float)h0[1];
    fV[t][2] = (float)h1[0]; fV[t][3] = (float)h1[1];
  }
  __syncthreads();

  const int q = t >> 1, hh = t & 1;
  float o0 = 0, o1 = 0, o2 = 0, o3 = 0;
  if (!hh) {
    const float4 v0 = *(const float4*)&fV[q][0];
    o0 = D9_0 * v0.x; o1 = D9_0 * v0.y; o2 = D9_0 * v0.z; o3 = D9_0 * v0.w;
  }

  float b[4];
#pragma unroll
  for (int p = 1; p <= 4; ++p) {
    const float cp = (p == 1) ? D9_1 : (p == 2) ? D9_2 : (p == 3) ? D9_3 : D9_4;
    col_pass(XL, fV, pkT, t);
    __syncthreads();
    row_pass(XL, pkT, t, b);
    if (!hh) {
      o0 += cp * b[0]; o1 += cp * b[1]; o2 += cp * b[2]; o3 += cp * b[3];
      if (p < 4) *(float4*)&fV[q][0] = make_float4(b[0], b[1], b[2], b[3]);
    }
    __syncthreads();
  }

  if (!hh) {
    ptm[(4 * g + 0) * 256 + q] = o0;
    ptm[(4 * g + 1) * 256 + q] = o1;
    ptm[(4 * g + 2) * 256 + q] = o2;
    ptm[(4 * g + 3) * 256 + q] = o3;
  }
}

// ---------------- K4: output assembly (reads P^T, coalesced) ----------------
__global__ __launch_bounds__(256) void k_out(const float* __restrict__ sp,
                                             const float* __restrict__ PT,
                                             const int* __restrict__ sel,
                                             float* __restrict__ out) {
  const int t = threadIdx.x;
  if (blockIdx.x < 128) {
    const int b = blockIdx.x;
    __shared__ float hd[256];
    hd[t] = sp[(size_t)b * Kd + t];
    __syncthreads();
    const int s = sel[b];
    if (s < 0) {
      out[(size_t)b * Kd + t] = hd[t];
    } else {
      const float* pt = PT + (size_t)s * MSZ;
      float acc = 0.f;
#pragma unroll 8
      for (int j = 0; j < 256; ++j) acc += pt[j * 256 + t] * hd[j];
      out[(size_t)b * Kd + t] = hd[t] + 0.1f * acc;
    }
  } else {
    const int ci = blockIdx.x - 128;
    const float4* in4 = (const float4*)sp;
    float4* out4 = (float4*)out;
    const int total = Bn * (Kd / 4);
    for (int i = ci * 256 + t; i < total; i += 2048 * 256) {
      const int pos = i & ((Kd / 4) - 1);
      if (pos >= Qd / 4) out4[i] = in4[i];
    }
  }
}

// ---------------- host ----------------
extern "C" void kernel_launch(void* const* d_in, const int* in_sizes, int n_in,
                              void* d_out, int out_size, void* d_ws, size_t ws_size,
                              hipStream_t stream) {
  (void)in_sizes; (void)n_in; (void)out_size; (void)ws_size;
  const float* sp = (const float*)d_in[0];
  const float* W1 = (const float*)d_in[1];
  const float* b1 = (const float*)d_in[2];
  const float* W2 = (const float*)d_in[3];
  const float* b2 = (const float*)d_in[4];
  const float* W3 = (const float*)d_in[5];
  const float* b3 = (const float*)d_in[6];
  const float* ops = (const float*)d_in[7];
  float* out = (float*)d_out;
  float* ws = (float*)d_ws;

  float* h1p  = ws + OFF_H1P;
  float* h1   = ws + OFF_H1;
  int*   sel  = (int*)(ws + OFF_SEL);
  float* part = ws + OFF_PART;
  float* PT   = ws + OFF_PT;
  unsigned int* XPa = (unsigned int*)(ws + OFF_XPA);
  unsigned int* XPb = (unsigned int*)(ws + OFF_XPB);

  k_gemm1<<<NCH, 256, 0, stream>>>(sp, W1, h1p);
  k_red<<<256, 256, 0, stream>>>(h1p, b1, h1);
  k_mlp<<<8, 256, 0, stream>>>(h1, W2, b2, W3, b3, sel);

  k_pack<<<192, 512, 0, stream>>>(ops, XPa, part);
  // 7 Muon iterations (first folds the 1/s scale), then degree-9 convergent
  k_it<<<192, 512, 0, stream>>>(XPa, XPb, part, 1);
  unsigned int *XPc = XPb, *XPn = XPa;
  for (int it = 1; it < 7; ++it) {
    k_it<<<192, 512, 0, stream>>>(XPc, XPn, part, 0);
    unsigned int* tp = XPc; XPc = XPn; XPn = tp;
  }
  k_d9<<<192, 512, 0, stream>>>(XPc, PT);

  k_out<<<128 + 2048, 256, 0, stream>>>(sp, PT, sel, out);
}

// Round 14
// 263.647 us; speedup vs baseline: 1.2044x; 1.0109x over previous
//
#include <hip/hip_runtime.h>
#include <math.h>

// ---------------- problem constants ----------------
constexpr int Bn  = 128;
constexpr int Kd  = 65536;    // magnitude dim (phase half of feats is zeros)
constexpr int F1  = 128;
constexpr int F2  = 64;
constexpr int NM  = 3;
constexpr int Qd  = 256;
constexpr int NCH = 512;      // split-K chunks for big GEMM
constexpr int KC  = 128;      // k per chunk
constexpr int MSZ = 256 * 256;
constexpr int XSZ = 256 * 128;  // u32 slots per packed matrix

// Muon (growth) quintic Newton-Schulz coefficients
#define MA 3.4445f
#define MB (-4.7750f)
#define MC 2.0315f
// degree-9 convergent NS: x*(315 - 420y + 378y^2 - 180y^3 + 35y^4)/128, y=x^2
#define D9_0 (315.f / 128.f)
#define D9_1 (-420.f / 128.f)
#define D9_2 (378.f / 128.f)
#define D9_3 (-180.f / 128.f)
#define D9_4 (35.f / 128.f)

// ---------------- ws layout (float offsets) ----------------
constexpr size_t OFF_H1P = 0;                                    // 8,388,608
constexpr size_t OFF_H1  = OFF_H1P + (size_t)NCH * Bn * F1;
constexpr size_t OFF_SEL = OFF_H1 + (size_t)Bn * F1;
constexpr size_t OFF_PART= OFF_SEL + 128;                        // 192 -> 256
constexpr size_t OFF_PT  = OFF_PART + 256;                       // NM*MSZ f32 (P^T)
constexpr size_t OFF_XPA = OFF_PT + (size_t)NM * MSZ;            // NM*XSZ u32
constexpr size_t OFF_XPB = OFF_XPA + (size_t)NM * XSZ;

// ---------------- f16 helpers ----------------
typedef __fp16 half2_t __attribute__((ext_vector_type(2)));
union HU { half2_t h; unsigned int u; };
__device__ __forceinline__ unsigned int pkh(float x, float y) {
  HU v; v.h = __builtin_amdgcn_cvt_pkrtz(x, y); return v.u;
}
__device__ __forceinline__ half2_t uh(unsigned int u) { HU v; v.u = u; return v.h; }

#if __has_builtin(__builtin_amdgcn_fdot2)
#define FDOT2(a, b, c) __builtin_amdgcn_fdot2((a), (b), (c), false)
#else
#define FDOT2(a, b, c) ((c) + (float)(a)[0] * (float)(b)[0] + (float)(a)[1] * (float)(b)[1])
#endif

// ---------------- bf16 helpers (MFMA GEMM) ----------------
typedef short bf16x8 __attribute__((ext_vector_type(8)));
typedef float f32x4 __attribute__((ext_vector_type(4)));
__device__ __forceinline__ unsigned short bh(float x) {   // RNE fp32 -> bf16
  unsigned int bx = __float_as_uint(x);
  return (unsigned short)((bx + 0x7FFFu + ((bx >> 16) & 1u)) >> 16);
}
__device__ __forceinline__ float bf(unsigned short h) {
  return __uint_as_float((unsigned int)h << 16);
}

// ---------------- K1: split-K magnitude GEMM via bf16-split MFMA (R10, proven) ----------------
__global__ __launch_bounds__(256) void k_gemm1(const float* __restrict__ sp,
                                               const float* __restrict__ W1,
                                               float* __restrict__ h1p) {
  __shared__ short Ah[128][72];
  __shared__ short Al[128][72];
  __shared__ short Bh[128][72];
  __shared__ short Bl[128][72];
  const int t = threadIdx.x;
  const int w = t >> 6, l = t & 63;
  const int l15 = l & 15, lg = l >> 4;
  const int ch = blockIdx.x;
  const size_t k0 = (size_t)ch * KC;
  const int srow = t >> 4;
  const int skq  = (t & 15) * 4;

  f32x4 acc[2][8];
#pragma unroll
  for (int r = 0; r < 2; ++r)
#pragma unroll
    for (int c = 0; c < 8; ++c) acc[r][c] = (f32x4){0.f, 0.f, 0.f, 0.f};

#pragma unroll
  for (int sub = 0; sub < 2; ++sub) {
    __syncthreads();
    const size_t kb = k0 + sub * 64 + skq;
#pragma unroll
    for (int rep = 0; rep < 8; ++rep) {
      const int row = srow + rep * 16;
      const float4 av = *(const float4*)(sp + (size_t)row * Kd + kb);
      const float4 bv = *(const float4*)(W1 + (size_t)row * (2 * Kd) + kb);
      float va[4] = {fabsf(av.x), fabsf(av.y), fabsf(av.z), fabsf(av.w)};
      float vb[4] = {bv.x, bv.y, bv.z, bv.w};
      unsigned short ha[4], la[4], hb[4], lb[4];
#pragma unroll
      for (int e = 0; e < 4; ++e) {
        ha[e] = bh(va[e]); la[e] = bh(va[e] - bf(ha[e]));
        hb[e] = bh(vb[e]); lb[e] = bh(vb[e] - bf(hb[e]));
      }
      *(uint2*)&Ah[row][skq] = make_uint2((unsigned)ha[0] | ((unsigned)ha[1] << 16),
                                          (unsigned)ha[2] | ((unsigned)ha[3] << 16));
      *(uint2*)&Al[row][skq] = make_uint2((unsigned)la[0] | ((unsigned)la[1] << 16),
                                          (unsigned)la[2] | ((unsigned)la[3] << 16));
      *(uint2*)&Bh[row][skq] = make_uint2((unsigned)hb[0] | ((unsigned)hb[1] << 16),
                                          (unsigned)hb[2] | ((unsigned)hb[3] << 16));
      *(uint2*)&Bl[row][skq] = make_uint2((unsigned)lb[0] | ((unsigned)lb[1] << 16),
                                          (unsigned)lb[2] | ((unsigned)lb[3] << 16));
    }
    __syncthreads();
#pragma unroll
    for (int ks = 0; ks < 2; ++ks) {
      const int ko = ks * 32 + lg * 8;
      bf16x8 afh[2], afl[2];
#pragma unroll
      for (int r = 0; r < 2; ++r) {
        const int row = w * 32 + r * 16 + l15;
        afh[r] = *(const bf16x8*)&Ah[row][ko];
        afl[r] = *(const bf16x8*)&Al[row][ko];
      }
#pragma unroll
      for (int c = 0; c < 8; ++c) {
        const int col = c * 16 + l15;
        const bf16x8 bfh = *(const bf16x8*)&Bh[col][ko];
        const bf16x8 bfl = *(const bf16x8*)&Bl[col][ko];
#pragma unroll
        for (int r = 0; r < 2; ++r) {
          acc[r][c] = __builtin_amdgcn_mfma_f32_16x16x32_bf16(afh[r], bfh, acc[r][c], 0, 0, 0);
          acc[r][c] = __builtin_amdgcn_mfma_f32_16x16x32_bf16(afh[r], bfl, acc[r][c], 0, 0, 0);
          acc[r][c] = __builtin_amdgcn_mfma_f32_16x16x32_bf16(afl[r], bfh, acc[r][c], 0, 0, 0);
        }
      }
    }
  }

  float* outp = h1p + (size_t)ch * (Bn * F1);
#pragma unroll
  for (int r = 0; r < 2; ++r)
#pragma unroll
    for (int c = 0; c < 8; ++c) {
      const int col = c * 16 + l15;
#pragma unroll
      for (int reg = 0; reg < 4; ++reg) {
        const int row = w * 32 + r * 16 + lg * 4 + reg;
        outp[row * F1 + col] = acc[r][c][reg];
      }
    }
}

// ---------------- K1b: reduce partials + bias + relu (512 chunks) ----------------
__global__ __launch_bounds__(256) void k_red(const float* __restrict__ h1p,
                                             const float* __restrict__ b1,
                                             float* __restrict__ h1) {
  const int t = threadIdx.x;
  const int ol = t & 63;
  const int g = t >> 6;
  const int o = blockIdx.x * 64 + ol;
  double s = 0.0;
#pragma unroll 8
  for (int c = g * 128; c < g * 128 + 128; ++c)
    s += (double)h1p[(size_t)c * (Bn * F1) + o];
  __shared__ double red[4][64];
  red[g][ol] = s;
  __syncthreads();
  if (g == 0) {
    const double v = red[0][ol] + red[1][ol] + red[2][ol] + red[3][ol];
    const float r = (float)v + b1[o & 127];
    h1[o] = fmaxf(r, 0.f);
  }
}

// ---------------- K2: small MLP + syndrome + selection ----------------
__global__ __launch_bounds__(256) void k_mlp(const float* __restrict__ h1,
                                             const float* __restrict__ W2,
                                             const float* __restrict__ b2,
                                             const float* __restrict__ W3,
                                             const float* __restrict__ b3,
                                             int* __restrict__ sel) {
  const int t = threadIdx.x;
  const int b0 = blockIdx.x * 16;
  __shared__ float h2s[16 * 64];
  for (int o = t; o < 16 * 64; o += 256) {
    const int bl = o >> 6, j = o & 63;
    const float* hr = h1 + (b0 + bl) * F1;
    const float* wr = W2 + j * F1;
    float s = b2[j];
    for (int k = 0; k < F1; ++k) s += hr[k] * wr[k];
    h2s[o] = fmaxf(s, 0.f);
  }
  __syncthreads();
  if (t < 16) {
    const int b = b0 + t;
    float best = -1.f;
    int bi = 0;
    bool needed = false;
    for (int j = 0; j < 8; ++j) {
      double s = (double)b3[j];
      const float* wr = W3 + j * F2;
      for (int k = 0; k < F2; ++k) s += (double)h2s[t * F2 + k] * (double)wr[k];
      const float a = fabsf((float)s);
      if (a > 1e-4f) needed = true;
      if (a > best) { best = a; bi = j; }
    }
    sel[b] = needed ? (bi % NM) : -1;
  }
}

// ---------------- NS pack: ops -> XP (row f16-pairs) + ssq partials ----------------
__global__ __launch_bounds__(512) void k_pack(const float* __restrict__ ops,
                                              unsigned int* __restrict__ XPD,
                                              float* __restrict__ part) {
  const int m = blockIdx.x >> 6, g = blockIdx.x & 63;
  const float* C = ops + (size_t)m * MSZ;
  unsigned int* xp = XPD + (size_t)m * XSZ;
  const int t = threadIdx.x;
  __shared__ float rq[8];

  const int r = g * 4 + (t >> 7), pp = t & 127;
  const float2 v = *(const float2*)&C[r * 256 + pp * 2];
  float ssq = v.x * v.x + v.y * v.y;
  xp[r * 128 + pp] = pkh(v.x, v.y);
#pragma unroll
  for (int o = 32; o; o >>= 1) ssq += __shfl_down(ssq, o, 64);
  if ((t & 63) == 0) rq[t >> 6] = ssq;
  __syncthreads();
  if (t == 0) {
    float s = 0.f;
#pragma unroll
    for (int q = 0; q < 8; ++q) s += rq[q];
    part[m * 64 + g] = s;
  }
}

// ---------------- LDS pass helpers ----------------
// col-pass: W = X^T V for 4 RHS; thread = (col c = t>>1, half hh = t&1).
// Per iteration ALL lanes read the SAME row r: XL[r][c>>1] is a 4-lane
// same-address broadcast on 16 distinct banks ((3r+cp)&31, pitch 131);
// V[r] is a single-address float4 broadcast. Conflict-free.
__device__ __forceinline__ void col_pass(const unsigned int (*__restrict__ XL)[131],
                                         const float (*__restrict__ V)[4],
                                         uint4* __restrict__ pkT,
                                         const int t) {
  const int c = t >> 1, hh = t & 1, sel = c & 1, cp = c >> 1;
  float a0 = 0, a1 = 0, a2 = 0, a3 = 0;
  const int rb = hh * 128;
#pragma unroll 8
  for (int i = 0; i < 128; ++i) {
    const int r = rb + i;
    const half2_t xh = uh(XL[r][cp]);
    const float x = (float)xh[sel];
    const float4 vr = *(const float4*)&V[r][0];
    a0 += x * vr.x; a1 += x * vr.y; a2 += x * vr.z; a3 += x * vr.w;
  }
  // combine the two row-halves (lanes 2c, 2c+1)
  a0 += __shfl_down(a0, 1, 2);
  a1 += __shfl_down(a1, 1, 2);
  a2 += __shfl_down(a2, 1, 2);
  a3 += __shfl_down(a3, 1, 2);
  // lane 4k holds W[2k][:], lane 4k+2 holds W[2k+1][:] -> pair and pack
  const float b0 = __shfl_down(a0, 2, 4);
  const float b1 = __shfl_down(a1, 2, 4);
  const float b2 = __shfl_down(a2, 2, 4);
  const float b3 = __shfl_down(a3, 2, 4);
  if ((t & 3) == 0)
    pkT[c >> 1] = make_uint4(pkh(a0, b0), pkh(a1, b1), pkh(a2, b2), pkh(a3, b3));
}

// row-pass: U = X W for 4 RHS; thread = (row q = t>>1, half hh = t&1)
// after the shfl, even lanes (hh==0) hold the full dot for row q.
__device__ __forceinline__ void row_pass(const unsigned int (*__restrict__ XL)[131],
                                         const uint4* __restrict__ pkT,
                                         const int t, float b[4]) {
  const int q = t >> 1, hh = t & 1;
  float b0 = 0, b1 = 0, b2 = 0, b3 = 0;
  const int kb = hh * 64;
#pragma unroll 8
  for (int kk = 0; kk < 64; ++kk) {
    const half2_t xh = uh(XL[q][kb + kk]);
    const uint4 wv = pkT[kb + kk];
    b0 = FDOT2(xh, uh(wv.x), b0);
    b1 = FDOT2(xh, uh(wv.y), b1);
    b2 = FDOT2(xh, uh(wv.z), b2);
    b3 = FDOT2(xh, uh(wv.w), b3);
  }
  b0 += __shfl_down(b0, 1, 2);
  b1 += __shfl_down(b1, 1, 2);
  b2 += __shfl_down(b2, 1, 2);
  b3 += __shfl_down(b3, 1, 2);
  b[0] = b0; b[1] = b1; b[2] = b2; b[3] = b3;
}

// ---------------- NS Muon iteration: one dispatch, X LDS-resident ----------------
// block owns cols j0..j0+3: X' = ca*V0 + cb*X(X^T V0) + cc*X(X^T(X(X^T V0)))
__global__ __launch_bounds__(512) void k_it(const unsigned int* __restrict__ XP,
                                            unsigned int* __restrict__ XPn,
                                            const float* __restrict__ part,
                                            const int first) {
  const int m = blockIdx.x >> 6, g = blockIdx.x & 63;
  const unsigned int* xp = XP + (size_t)m * XSZ;
  unsigned int* xpn = XPn + (size_t)m * XSZ;
  const int t = threadIdx.x;

  __shared__ unsigned int XL[256][131];
  __shared__ float fV[256][4];
  __shared__ float fU[256][4];
  __shared__ uint4 pkT[132];
  __shared__ float sSh;

  if (first && t < 64) {
    float v = part[m * 64 + t];
#pragma unroll
    for (int o = 32; o; o >>= 1) v += __shfl_down(v, o, 64);
    if (t == 0) sSh = v;
  }

  // stage X into LDS (coalesced flat copy)
#pragma unroll 8
  for (int i = 0; i < 64; ++i) {
    const int flat = i * 512 + t;
    XL[flat >> 7][flat & 127] = xp[flat];
  }
  __syncthreads();

  float ca = MA, cb = MB, cc = MC;
  if (first) {
    const float s = 0.15f * sqrtf(sSh);  // 1.2 * 2||C||_F / sqrt(256)
    const float is = 1.f / s, is2 = is * is;
    ca = MA * is; cb = MB * is * is2; cc = MC * is * is2 * is2;
  }

  // stage V0 = X[:, 4g..4g+3] (f32)
  if (t < 256) {
    const half2_t h0 = uh(XL[t][2 * g]), h1 = uh(XL[t][2 * g + 1]);
    fV[t][0] = (float)h0[0]; fV[t][1] = (float)h0[1];
    fV[t][2] = (float)h1[0]; fV[t][3] = (float)h1[1];
  }
  __syncthreads();

  col_pass(XL, fV, pkT, t);   // W1 = X^T V0
  __syncthreads();
  float b[4];
  row_pass(XL, pkT, t, b);    // U1 = X W1
  const int q = t >> 1, hh = t & 1;
  if (!hh) *(float4*)&fU[q][0] = make_float4(b[0], b[1], b[2], b[3]);
  __syncthreads();

  col_pass(XL, fU, pkT, t);   // W2 = X^T U1
  __syncthreads();
  row_pass(XL, pkT, t, b);    // U2 = X W2
  if (!hh) {
    const float4 v0 = *(const float4*)&fV[q][0];
    const float4 u1 = *(const float4*)&fU[q][0];
    const float r0 = ca * v0.x + cb * u1.x + cc * b[0];
    const float r1 = ca * v0.y + cb * u1.y + cc * b[1];
    const float r2 = ca * v0.z + cb * u1.z + cc * b[2];
    const float r3 = ca * v0.w + cb * u1.w + cc * b[3];
    xpn[q * 128 + 2 * g]     = pkh(r0, r1);
    xpn[q * 128 + 2 * g + 1] = pkh(r2, r3);
  }
}

// ---------------- NS degree-9 convergent final: writes P^T fp32 ----------------
__global__ __launch_bounds__(512) void k_d9(const unsigned int* __restrict__ XP,
                                            float* __restrict__ PT) {
  const int m = blockIdx.x >> 6, g = blockIdx.x & 63;
  const unsigned int* xp = XP + (size_t)m * XSZ;
  float* ptm = PT + (size_t)m * MSZ;
  const int t = threadIdx.x;

  __shared__ unsigned int XL[256][131];
  __shared__ float fV[256][4];
  __shared__ uint4 pkT[132];

#pragma unroll 8
  for (int i = 0; i < 64; ++i) {
    const int flat = i * 512 + t;
    XL[flat >> 7][flat & 127] = xp[flat];
  }
  __syncthreads();
  if (t < 256) {
    const half2_t h0 = uh(XL[t][2 * g]), h1 = uh(XL[t][2 * g + 1]);
    fV[t][0] = (float)h0[0]; fV[t][1] = (float)h0[1];
    fV[t][2] = (float)h1[0]; fV[t][3] = (float)h1[1];
  }
  __syncthreads();

  const int q = t >> 1, hh = t & 1;
  float o0 = 0, o1 = 0, o2 = 0, o3 = 0;
  if (!hh) {
    const float4 v0 = *(const float4*)&fV[q][0];
    o0 = D9_0 * v0.x; o1 = D9_0 * v0.y; o2 = D9_0 * v0.z; o3 = D9_0 * v0.w;
  }

  float b[4];
#pragma unroll
  for (int p = 1; p <= 4; ++p) {
    const float cp = (p == 1) ? D9_1 : (p == 2) ? D9_2 : (p == 3) ? D9_3 : D9_4;
    col_pass(XL, fV, pkT, t);
    __syncthreads();
    row_pass(XL, pkT, t, b);
    if (!hh) {
      o0 += cp * b[0]; o1 += cp * b[1]; o2 += cp * b[2]; o3 += cp * b[3];
      if (p < 4) *(float4*)&fV[q][0] = make_float4(b[0], b[1], b[2], b[3]);
    }
    __syncthreads();
  }

  if (!hh) {
    ptm[(4 * g + 0) * 256 + q] = o0;
    ptm[(4 * g + 1) * 256 + q] = o1;
    ptm[(4 * g + 2) * 256 + q] = o2;
    ptm[(4 * g + 3) * 256 + q] = o3;
  }
}

// ---------------- K4: output assembly (reads P^T, coalesced) ----------------
__global__ __launch_bounds__(256) void k_out(const float* __restrict__ sp,
                                             const float* __restrict__ PT,
                                             const int* __restrict__ sel,
                                             float* __restrict__ out) {
  const int t = threadIdx.x;
  if (blockIdx.x < 128) {
    const int b = blockIdx.x;
    __shared__ float hd[256];
    hd[t] = sp[(size_t)b * Kd + t];
    __syncthreads();
    const int s = sel[b];
    if (s < 0) {
      out[(size_t)b * Kd + t] = hd[t];
    } else {
      const float* pt = PT + (size_t)s * MSZ;
      float acc = 0.f;
#pragma unroll 8
      for (int j = 0; j < 256; ++j) acc += pt[j * 256 + t] * hd[j];
      out[(size_t)b * Kd + t] = hd[t] + 0.1f * acc;
    }
  } else {
    const int ci = blockIdx.x - 128;
    const float4* in4 = (const float4*)sp;
    float4* out4 = (float4*)out;
    const int total = Bn * (Kd / 4);
    for (int i = ci * 256 + t; i < total; i += 2048 * 256) {
      const int pos = i & ((Kd / 4) - 1);
      if (pos >= Qd / 4) out4[i] = in4[i];
    }
  }
}

// ---------------- host ----------------
extern "C" void kernel_launch(void* const* d_in, const int* in_sizes, int n_in,
                              void* d_out, int out_size, void* d_ws, size_t ws_size,
                              hipStream_t stream) {
  (void)in_sizes; (void)n_in; (void)out_size; (void)ws_size;
  const float* sp = (const float*)d_in[0];
  const float* W1 = (const float*)d_in[1];
  const float* b1 = (const float*)d_in[2];
  const float* W2 = (const float*)d_in[3];
  const float* b2 = (const float*)d_in[4];
  const float* W3 = (const float*)d_in[5];
  const float* b3 = (const float*)d_in[6];
  const float* ops = (const float*)d_in[7];
  float* out = (float*)d_out;
  float* ws = (float*)d_ws;

  float* h1p  = ws + OFF_H1P;
  float* h1   = ws + OFF_H1;
  int*   sel  = (int*)(ws + OFF_SEL);
  float* part = ws + OFF_PART;
  float* PT   = ws + OFF_PT;
  unsigned int* XPa = (unsigned int*)(ws + OFF_XPA);
  unsigned int* XPb = (unsigned int*)(ws + OFF_XPB);

  k_gemm1<<<NCH, 256, 0, stream>>>(sp, W1, h1p);
  k_red<<<256, 256, 0, stream>>>(h1p, b1, h1);
  k_mlp<<<8, 256, 0, stream>>>(h1, W2, b2, W3, b3, sel);

  k_pack<<<192, 512, 0, stream>>>(ops, XPa, part);
  // 7 Muon iterations (first folds the 1/s scale), then degree-9 convergent
  k_it<<<192, 512, 0, stream>>>(XPa, XPb, part, 1);
  unsigned int *XPc = XPb, *XPn = XPa;
  for (int it = 1; it < 7; ++it) {
    k_it<<<192, 512, 0, stream>>>(XPc, XPn, part, 0);
    unsigned int* tp = XPc; XPc = XPn; XPn = tp;
  }
  k_d9<<<192, 512, 0, stream>>>(XPc, PT);

  k_out<<<128 + 2048, 256, 0, stream>>>(sp, PT, sel, out);
}